// Round 7
// baseline (50.555 us; speedup 1.0000x reference)
//
#include <hip/hip_runtime.h>

#define NDIM   16
#define MCOLS  2048
#define NANG   120           // 16*15/2
#define BLOCK  256
#define COLS_PER_WG 1024     // 256 threads * 4 cols (float4)

typedef float f32x4 __attribute__((ext_vector_type(4)));

// ---------- Kernel 1: one 64-thread wave per block computes mus-scaled R into ws.
__global__ __launch_bounds__(64) void build_R_kernel(
    const float* __restrict__ angles,
    const float* __restrict__ mus,
    float* __restrict__ Rws)
{
    const int b    = blockIdx.x;
    const int lane = threadIdx.x;
    __shared__ float c_lds[NANG];
    __shared__ float s_lds[NANG];

#pragma unroll
    for (int rep = 0; rep < 2; ++rep) {
        const int k = lane + rep * 64;
        if (k < NANG) {
            float sv, cv;
            sincosf(angles[b * NANG + k], &sv, &cv);
            c_lds[k] = cv;
            s_lds[k] = sv;
        }
    }
    __syncthreads();

    if (lane < NDIM) {
        const int j = lane;
        float m[NDIM];
#pragma unroll
        for (int r = 0; r < NDIM; ++r) m[r] = (r == j) ? 1.0f : 0.0f;
        int k = 0;
#pragma unroll
        for (int iTop = 0; iTop < NDIM - 1; ++iTop) {
            float vt = m[iTop];
#pragma unroll
            for (int iBtm = iTop + 1; iBtm < NDIM; ++iBtm) {
                const float c  = c_lds[k];
                const float s  = s_lds[k];
                const float vb = m[iBtm];
                const float nvt = c * vt - s * vb;
                m[iBtm] = s * vt + c * vb;
                vt = nvt;
                ++k;
            }
            m[iTop] = vt;
        }
#pragma unroll
        for (int r = 0; r < NDIM; ++r)
            Rws[b * (NDIM * NDIM) + r * NDIM + j] = mus[b * NDIM + r] * m[r];
    }
}

// ---------- Kernel 2: barrier-free streaming out = R @ X.
// Each wave redundantly copies the (identical) R values into LDS, so only its
// own wave-local ds_write -> ds_read ordering is needed: no __syncthreads,
// waves never wait on each other -> pure streaming.
__global__ __launch_bounds__(BLOCK) void apply_kernel(
    const float* __restrict__ X,
    const float* __restrict__ Rws,
    float* __restrict__ out)
{
    const int wg   = blockIdx.x;
    const int b    = wg >> 1;
    const int half = wg & 1;
    const int tid  = threadIdx.x;
    const int lane = tid & 63;
    __shared__ __align__(16) float R_lds[NDIM * NDIM];

    const int col = half * COLS_PER_WG + tid * 4;
    const float* Xb = X   + (size_t)b * NDIM * MCOLS;
    float*       Ob = out + (size_t)b * NDIM * MCOLS;

    // Issue phase-0 X loads first: their latency covers the R fetch below.
    f32x4 x[8];
#pragma unroll
    for (int j = 0; j < 8; ++j)
        x[j] = *reinterpret_cast<const f32x4*>(Xb + j * MCOLS + col);

    // Every wave writes the full R (same values) - benign race, no barrier.
    *reinterpret_cast<f32x4*>(&R_lds[lane * 4]) =
        *reinterpret_cast<const f32x4*>(&Rws[b * (NDIM * NDIM) + lane * 4]);

    f32x4 acc[NDIM];

    // Phase 0: rows 0..7
#pragma unroll
    for (int r = 0; r < NDIM; ++r) {
        acc[r] = R_lds[r * NDIM + 0] * x[0];
#pragma unroll
        for (int q = 1; q < 8; ++q)
            acc[r] += R_lds[r * NDIM + q] * x[q];
    }

    // Phase 1: rows 8..15 (reuse x[])
#pragma unroll
    for (int j = 0; j < 8; ++j)
        x[j] = *reinterpret_cast<const f32x4*>(Xb + (8 + j) * MCOLS + col);
#pragma unroll
    for (int r = 0; r < NDIM; ++r) {
#pragma unroll
        for (int q = 0; q < 8; ++q)
            acc[r] += R_lds[r * NDIM + 8 + q] * x[q];
    }

    // Write-once output: nontemporal stores.
#pragma unroll
    for (int r = 0; r < NDIM; ++r)
        __builtin_nontemporal_store(acc[r], reinterpret_cast<f32x4*>(Ob + r * MCOLS + col));
}

// ---------- Fallback fused kernel (used only if ws is too small) — R6 version.
__global__ __launch_bounds__(BLOCK) void soot_fused_kernel(
    const float* __restrict__ X,
    const float* __restrict__ angles,
    const float* __restrict__ mus,
    float* __restrict__ out)
{
    __shared__ float c_lds[NANG];
    __shared__ float s_lds[NANG];
    __shared__ __align__(16) float R_lds[NDIM * NDIM];

    const int wg   = blockIdx.x;
    const int b    = wg >> 1;
    const int half = wg & 1;
    const int tid  = threadIdx.x;

    if (tid < 64) {
#pragma unroll
        for (int rep = 0; rep < 2; ++rep) {
            const int k = tid + rep * 64;
            if (k < NANG) {
                float a = angles[b * NANG + k];
                float sv, cv;
                sincosf(a, &sv, &cv);
                c_lds[k] = cv;
                s_lds[k] = sv;
            }
        }
    }
    __syncthreads();

    if (tid < NDIM) {
        const int j = tid;
        float m[NDIM];
#pragma unroll
        for (int r = 0; r < NDIM; ++r) m[r] = (r == j) ? 1.0f : 0.0f;
        int k = 0;
#pragma unroll
        for (int iTop = 0; iTop < NDIM - 1; ++iTop) {
            float vt = m[iTop];
#pragma unroll
            for (int iBtm = iTop + 1; iBtm < NDIM; ++iBtm) {
                const float c  = c_lds[k];
                const float s  = s_lds[k];
                const float vb = m[iBtm];
                const float nvt = c * vt - s * vb;
                m[iBtm] = s * vt + c * vb;
                vt = nvt;
                ++k;
            }
            m[iTop] = vt;
        }
#pragma unroll
        for (int r = 0; r < NDIM; ++r)
            R_lds[r * NDIM + j] = mus[b * NDIM + r] * m[r];
    }
    __syncthreads();

    const int col = half * COLS_PER_WG + tid * 4;
    const float* Xb = X   + (size_t)b * NDIM * MCOLS;
    float*       Ob = out + (size_t)b * NDIM * MCOLS;

    f32x4 x[8];
    f32x4 acc[NDIM];

#pragma unroll
    for (int j = 0; j < 8; ++j)
        x[j] = *reinterpret_cast<const f32x4*>(Xb + j * MCOLS + col);
#pragma unroll
    for (int r = 0; r < NDIM; ++r) {
        acc[r] = R_lds[r * NDIM + 0] * x[0];
#pragma unroll
        for (int q = 1; q < 8; ++q)
            acc[r] += R_lds[r * NDIM + q] * x[q];
    }

#pragma unroll
    for (int j = 0; j < 8; ++j)
        x[j] = *reinterpret_cast<const f32x4*>(Xb + (8 + j) * MCOLS + col);
#pragma unroll
    for (int r = 0; r < NDIM; ++r) {
#pragma unroll
        for (int q = 0; q < 8; ++q)
            acc[r] += R_lds[r * NDIM + 8 + q] * x[q];
    }

#pragma unroll
    for (int r = 0; r < NDIM; ++r)
        __builtin_nontemporal_store(acc[r], reinterpret_cast<f32x4*>(Ob + r * MCOLS + col));
}

extern "C" void kernel_launch(void* const* d_in, const int* in_sizes, int n_in,
                              void* d_out, int out_size, void* d_ws, size_t ws_size,
                              hipStream_t stream) {
    const float* X      = (const float*)d_in[0];
    const float* angles = (const float*)d_in[1];
    const float* mus    = (const float*)d_in[2];
    float* out          = (float*)d_out;

    const int nblks = in_sizes[1] / NANG;          // 1024
    const size_t ws_needed = (size_t)nblks * NDIM * NDIM * sizeof(float);

    if (ws_size >= ws_needed) {
        float* Rws = (float*)d_ws;
        hipLaunchKernelGGL(build_R_kernel, dim3(nblks), dim3(64), 0, stream,
                           angles, mus, Rws);
        hipLaunchKernelGGL(apply_kernel,
                           dim3(nblks * (MCOLS / COLS_PER_WG)), dim3(BLOCK), 0, stream,
                           X, Rws, out);
    } else {
        hipLaunchKernelGGL(soot_fused_kernel,
                           dim3(nblks * (MCOLS / COLS_PER_WG)), dim3(BLOCK), 0, stream,
                           X, angles, mus, out);
    }
}